// Round 1
// baseline (1215.748 us; speedup 1.0000x reference)
//
#include <hip/hip_runtime.h>
#include <hip/hip_bf16.h>
#include <stdint.h>

// Problem constants
#define B_  32
#define S_  2048
#define H_  1024
#define K_  2048   // 2H, GEMM reduction dim
#define M_  65536  // B*S

// GEMM tile config
#define BM  128
#define BN  128
#define BK  32
#define LDK 40     // padded LDS row stride (bf16 elems); 40*2=80B = 5*16B keeps 16B alignment

typedef __bf16 bf16x8 __attribute__((ext_vector_type(8)));
typedef float  f32x4  __attribute__((ext_vector_type(4)));

__device__ __forceinline__ unsigned short f2bf(float x) {
    // round-to-nearest-even fp32 -> bf16
    unsigned u = __builtin_bit_cast(unsigned, x);
    u += 0x7fffu + ((u >> 16) & 1u);
    return (unsigned short)(u >> 16);
}

__device__ __forceinline__ float tanh_fast(float x) {
    // tanh(x) = 1 - 2/(exp(2x)+1); exact at +/-inf saturation
    float e = __expf(2.0f * x);
    return 1.0f - 2.0f / (e + 1.0f);
}

// ---------------------------------------------------------------- cast W_enc -> bf16
__global__ __launch_bounds__(256) void cast_k(const float* __restrict__ in,
                                              unsigned short* __restrict__ o, int n4) {
    int i = blockIdx.x * 256 + threadIdx.x;
    if (i < n4) {
        float4 v = *(const float4*)(in + (long)i * 4);
        unsigned short h0 = f2bf(v.x), h1 = f2bf(v.y), h2 = f2bf(v.z), h3 = f2bf(v.w);
        uint2 pk;
        pk.x = (unsigned)h0 | ((unsigned)h1 << 16);
        pk.y = (unsigned)h2 | ((unsigned)h3 << 16);
        *(uint2*)(o + (long)i * 4) = pk;
    }
}

// ---------------------------------------------------------------- dec = dec_state @ W_dec^T
// grid (H/4, B), 256 thr; one wave per (b,h)
__global__ __launch_bounds__(256) void dec_k(const float* __restrict__ ds,
                                             const float* __restrict__ Wd,
                                             float* __restrict__ decv) {
    const int b = blockIdx.y;
    const int w = threadIdx.x >> 6, lane = threadIdx.x & 63;
    const int h = blockIdx.x * 4 + w;
    const float* wr = Wd + (long)h * H_;
    const float* dr = ds + (long)b * H_;
    float acc = 0.f;
#pragma unroll
    for (int i = 0; i < 4; i++) {
        int idx = lane * 4 + i * 256;
        float4 a = *(const float4*)(wr + idx);
        float4 d = *(const float4*)(dr + idx);
        acc += a.x * d.x + a.y * d.y + a.z * d.z + a.w * d.w;
    }
    for (int m2 = 1; m2 < 64; m2 <<= 1) acc += __shfl_xor(acc, m2, 64);
    if (lane == 0) decv[(long)b * H_ + h] = acc;
}

// ---------------------------------------------------------------- fused GEMM + tanh-energy
// C[m,n] = sum_k A[m,k]*Wenc[n,k]; epilogue: pe[nb][m] = sum_{n in block} tanh(dec+C)*Weng[n]
// grid (8 = N/BN, 512 = M/BM), 256 thr (4 waves, 2x2 of 64x64)
__global__ __launch_bounds__(256) void gemm_energy(const float* __restrict__ A,
                                                   const unsigned short* __restrict__ Bw,
                                                   const float* __restrict__ decv,
                                                   const float* __restrict__ Weng,
                                                   float* __restrict__ pe) {
    __shared__ __align__(16) unsigned short Asm[BM * LDK];
    __shared__ __align__(16) unsigned short Bsm[BN * LDK];
    __shared__ float esum[2][BM];

    const int nb = blockIdx.x, mb = blockIdx.y;
    const int t = threadIdx.x;
    const int lane = t & 63, w = t >> 6;
    const int wm = w >> 1, wn = w & 1;
    const int r = lane & 15, g = lane >> 4;

    f32x4 acc[4][4];
#pragma unroll
    for (int mi = 0; mi < 4; mi++)
#pragma unroll
        for (int ni = 0; ni < 4; ni++)
#pragma unroll
            for (int k = 0; k < 4; k++) acc[mi][ni][k] = 0.f;

    const float* Abase = A + (long)mb * BM * K_;
    const unsigned short* Bbase = Bw + (long)nb * BN * K_;

    for (int kt = 0; kt < K_; kt += BK) {
        __syncthreads();
        // stage A: fp32 load -> bf16 cvt -> LDS (padded)
#pragma unroll
        for (int i = 0; i < 4; i++) {
            int f = t + 256 * i;
            int row = f >> 3, c4 = (f & 7) << 2;
            float4 v = *(const float4*)(Abase + (long)row * K_ + kt + c4);
            unsigned short h0 = f2bf(v.x), h1 = f2bf(v.y), h2 = f2bf(v.z), h3 = f2bf(v.w);
            uint2 pk;
            pk.x = (unsigned)h0 | ((unsigned)h1 << 16);
            pk.y = (unsigned)h2 | ((unsigned)h3 << 16);
            *(uint2*)&Asm[row * LDK + c4] = pk;
        }
        // stage B: already bf16, 16B vector copies
#pragma unroll
        for (int j = 0; j < 2; j++) {
            int u = t + 256 * j;
            int row = u >> 2, c8 = (u & 3) << 3;
            uint4 v = *(const uint4*)(Bbase + (long)row * K_ + kt + c8);
            *(uint4*)&Bsm[row * LDK + c8] = v;
        }
        __syncthreads();
        // fragments: lane holds row (lane&15), k-chunk (lane>>4)*8..+8
        bf16x8 af[4], bfr[4];
#pragma unroll
        for (int mi = 0; mi < 4; mi++)
            af[mi] = *(const bf16x8*)&Asm[(wm * 64 + mi * 16 + r) * LDK + g * 8];
#pragma unroll
        for (int ni = 0; ni < 4; ni++)
            bfr[ni] = *(const bf16x8*)&Bsm[(wn * 64 + ni * 16 + r) * LDK + g * 8];
#pragma unroll
        for (int mi = 0; mi < 4; mi++)
#pragma unroll
            for (int ni = 0; ni < 4; ni++)
                acc[mi][ni] = __builtin_amdgcn_mfma_f32_16x16x32_bf16(af[mi], bfr[ni],
                                                                     acc[mi][ni], 0, 0, 0);
    }

    // ---- epilogue: partial energies for this 128-col slab ----
    const int b = mb >> 4;  // S/BM = 16 m-blocks per batch; tiles never straddle b
    float wv[4], dv[4];
#pragma unroll
    for (int ni = 0; ni < 4; ni++) {
        int h = nb * BN + wn * 64 + ni * 16 + r;  // C/D col = lane&15
        wv[ni] = Weng[h];
        dv[ni] = decv[b * H_ + h];
    }
    float rs[4][4];
#pragma unroll
    for (int mi = 0; mi < 4; mi++)
#pragma unroll
        for (int rr = 0; rr < 4; rr++) rs[mi][rr] = 0.f;
#pragma unroll
    for (int mi = 0; mi < 4; mi++)
#pragma unroll
        for (int ni = 0; ni < 4; ni++)
#pragma unroll
            for (int rr = 0; rr < 4; rr++)
                rs[mi][rr] += wv[ni] * tanh_fast(dv[ni] + acc[mi][ni][rr]);
    // reduce over the 16 lanes (cols) of each lane-group
#pragma unroll
    for (int m2 = 1; m2 < 16; m2 <<= 1)
#pragma unroll
        for (int mi = 0; mi < 4; mi++)
#pragma unroll
            for (int rr = 0; rr < 4; rr++)
                rs[mi][rr] += __shfl_xor(rs[mi][rr], m2, 64);
    if (r == 0) {
#pragma unroll
        for (int mi = 0; mi < 4; mi++)
#pragma unroll
            for (int rr = 0; rr < 4; rr++)
                esum[wn][wm * 64 + mi * 16 + g * 4 + rr] = rs[mi][rr];  // row=(lane>>4)*4+reg
    }
    __syncthreads();
    if (t < BM) pe[(long)nb * M_ + (long)mb * BM + t] = esum[0][t] + esum[1][t];
}

// ---------------------------------------------------------------- masked softmax over s
// grid B, 256 thr; 8 s per thread
__global__ __launch_bounds__(256) void softmax_k(const float* __restrict__ pe,
                                                 const int* __restrict__ slen,
                                                 float* __restrict__ alph) {
    const int b = blockIdx.x, t = threadIdx.x;
    const int len = slen[b];
    __shared__ float sh[4];
    const float NEG = -__builtin_inff();
    float e[8];
    float mx = NEG;
#pragma unroll
    for (int i = 0; i < 8; i++) {
        int s = t + i * 256;
        float v = 0.f;
#pragma unroll
        for (int p = 0; p < 8; p++) v += pe[(long)p * M_ + b * S_ + s];
        v = (s < len) ? v : NEG;
        e[i] = v;
        mx = fmaxf(mx, v);
    }
    for (int m2 = 1; m2 < 64; m2 <<= 1) mx = fmaxf(mx, __shfl_xor(mx, m2, 64));
    if ((t & 63) == 0) sh[t >> 6] = mx;
    __syncthreads();
    mx = fmaxf(fmaxf(sh[0], sh[1]), fmaxf(sh[2], sh[3]));
    float sum = 0.f;
#pragma unroll
    for (int i = 0; i < 8; i++) {
        float x = (e[i] == NEG) ? 0.f : __expf(e[i] - mx);
        e[i] = x;
        sum += x;
    }
    for (int m2 = 1; m2 < 64; m2 <<= 1) sum += __shfl_xor(sum, m2, 64);
    __syncthreads();
    if ((t & 63) == 0) sh[t >> 6] = sum;
    __syncthreads();
    sum = sh[0] + sh[1] + sh[2] + sh[3];
    float inv = 1.0f / sum;
#pragma unroll
    for (int i = 0; i < 8; i++) alph[b * S_ + t + i * 256] = e[i] * inv;
}

// ---------------------------------------------------------------- context = alphas @ enc_state
// grid (16, B): x -> ec = x&1 (half of 2H), sc = x>>3.. (s-chunk of 256); 256 thr, float4/thread
__global__ __launch_bounds__(256) void context_k(const float* __restrict__ enc,
                                                 const float* __restrict__ alph,
                                                 const int* __restrict__ slen,
                                                 float* __restrict__ out) {
    const int b = blockIdx.y;
    const int x = blockIdx.x;
    const int ec = x & 1, sc = x >> 1;  // 2 e-halves x 8 s-chunks
    const int len = slen[b];
    const int s0 = sc * 256;
    if (s0 >= len) return;  // alphas there are exactly 0
    const int send = min(s0 + 256, len);
    __shared__ float al[256];
    const int t = threadIdx.x;
    al[t] = alph[b * S_ + s0 + t];
    __syncthreads();
    const int e0 = ec * 1024 + t * 4;
    float ax = 0.f, ay = 0.f, az = 0.f, aw = 0.f;
    const float* base = enc + ((long)b * S_ + s0) * K_ + e0;
#pragma unroll 4
    for (int s = s0; s < send; ++s) {
        float a = al[s - s0];
        float4 v = *(const float4*)base;
        ax += a * v.x; ay += a * v.y; az += a * v.z; aw += a * v.w;
        base += K_;
    }
    float* o = out + (long)b * K_ + e0;
    atomicAdd(o + 0, ax);
    atomicAdd(o + 1, ay);
    atomicAdd(o + 2, az);
    atomicAdd(o + 3, aw);
}

extern "C" void kernel_launch(void* const* d_in, const int* in_sizes, int n_in,
                              void* d_out, int out_size, void* d_ws, size_t ws_size,
                              hipStream_t stream) {
    const float* dec_state = (const float*)d_in[0];  // [32,1,1024]
    const float* enc_state = (const float*)d_in[1];  // [32,2048,2048]
    const int*   src_len   = (const int*)d_in[2];    // [32]
    const float* W_enc     = (const float*)d_in[3];  // [1024,2048]
    const float* W_dec     = (const float*)d_in[4];  // [1024,1024]
    const float* W_energy  = (const float*)d_in[5];  // [1,1024]
    float* out = (float*)d_out;  // [0,65536): context [32,2048]; [65536,131072): alphas [32,2048]

    char* ws = (char*)d_ws;
    float* decv = (float*)ws;                                         // 128 KB
    float* pe   = (float*)(ws + 131072);                              // 8*65536 f32 = 2 MB
    unsigned short* Wenc_bf = (unsigned short*)(ws + 131072 + 2097152); // 4 MB
    float* alph = out + 65536;

    // context region accumulated via atomics -> zero it (ws/d_out are poisoned 0xAA)
    hipMemsetAsync(out, 0, 65536 * sizeof(float), stream);

    cast_k<<<2048, 256, 0, stream>>>(W_enc, Wenc_bf, 524288);
    dec_k<<<dim3(H_ / 4, B_), 256, 0, stream>>>(dec_state, W_dec, decv);
    gemm_energy<<<dim3(8, 512), 256, 0, stream>>>(enc_state, Wenc_bf, decv, W_energy, pe);
    softmax_k<<<B_, 256, 0, stream>>>(pe, src_len, alph);
    context_k<<<dim3(16, B_), 256, 0, stream>>>(enc_state, alph, src_len, out);
}

// Round 2
// 1154.303 us; speedup vs baseline: 1.0532x; 1.0532x over previous
//
#include <hip/hip_runtime.h>
#include <hip/hip_bf16.h>
#include <stdint.h>

// Problem constants
#define B_  32
#define S_  2048
#define H_  1024
#define K_  2048   // 2H, GEMM reduction dim
#define M_  65536  // B*S

// GEMM tile config
#define BM  128
#define BN  128
#define BK  32
#define LDK 40     // padded LDS row stride for A (bf16 elems); 80B = 5*16B keeps 16B align

typedef __bf16 bf16x8 __attribute__((ext_vector_type(8)));
typedef float  f32x4  __attribute__((ext_vector_type(4)));

__device__ __forceinline__ unsigned short f2bf(float x) {
    unsigned u = __builtin_bit_cast(unsigned, x);
    u += 0x7fffu + ((u >> 16) & 1u);
    return (unsigned short)(u >> 16);
}

// packed fp32x2 -> bf16x2 (single v_cvt_pk_bf16_f32 on gfx950)
__device__ __forceinline__ unsigned pk_bf16(float x, float y) {
#if __has_builtin(__builtin_amdgcn_cvt_pk_bf16_f32)
    auto r = __builtin_amdgcn_cvt_pk_bf16_f32(x, y);
    static_assert(sizeof(r) == 4, "cvt_pk_bf16 size");
    return __builtin_bit_cast(unsigned, r);
#else
    return ((unsigned)f2bf(x)) | ((unsigned)f2bf(y) << 16);
#endif
}

__device__ __forceinline__ float tanh_fast(float x) {
    float e = __expf(2.0f * x);
    return 1.0f - 2.0f / (e + 1.0f);
}

// ---------------------------------------------------------------- cast W_enc -> bf16
__global__ __launch_bounds__(256) void cast_k(const float* __restrict__ in,
                                              unsigned short* __restrict__ o, int n4) {
    int i = blockIdx.x * 256 + threadIdx.x;
    if (i < n4) {
        float4 v = *(const float4*)(in + (long)i * 4);
        uint2 pk;
        pk.x = pk_bf16(v.x, v.y);
        pk.y = pk_bf16(v.z, v.w);
        *(uint2*)(o + (long)i * 4) = pk;
    }
}

// ---------------------------------------------------------------- dec = dec_state @ W_dec^T
__global__ __launch_bounds__(256) void dec_k(const float* __restrict__ ds,
                                             const float* __restrict__ Wd,
                                             float* __restrict__ decv) {
    const int b = blockIdx.y;
    const int w = threadIdx.x >> 6, lane = threadIdx.x & 63;
    const int h = blockIdx.x * 4 + w;
    const float* wr = Wd + (long)h * H_;
    const float* dr = ds + (long)b * H_;
    float acc = 0.f;
#pragma unroll
    for (int i = 0; i < 4; i++) {
        int idx = lane * 4 + i * 256;
        float4 a = *(const float4*)(wr + idx);
        float4 d = *(const float4*)(dr + idx);
        acc += a.x * d.x + a.y * d.y + a.z * d.z + a.w * d.w;
    }
    for (int m2 = 1; m2 < 64; m2 <<= 1) acc += __shfl_xor(acc, m2, 64);
    if (lane == 0) decv[(long)b * H_ + h] = acc;
}

// ---------------------------------------------------------------- fused GEMM + tanh-energy
// 1-D grid 4096, decoded so the 8 nb-blocks of an mb share one XCD (L2 A-tile reuse).
__global__ __launch_bounds__(256) void gemm_energy(const float* __restrict__ A,
                                                   const unsigned short* __restrict__ Bw,
                                                   const float* __restrict__ decv,
                                                   const float* __restrict__ Weng,
                                                   float* __restrict__ pe) {
    __shared__ __align__(16) unsigned short Asm[BM * LDK];
    __shared__ __align__(1024) unsigned short Bsm[BN * BK];  // unpadded: DMA-contiguous
    __shared__ float esum[2][BM];

    // XCD-group swizzle: ids of one mb-group are {c, c+8, ..., c+56} -> same XCD (id%8),
    // adjacent in dispatch -> ~lockstep A-tile sharing through that XCD's L2.
    const int L = blockIdx.x;
    const int xcd = L & 7;
    const int slot = L >> 3;
    const int nb = slot & 7;
    const int mb = (slot >> 3) * 8 + xcd;

    const int t = threadIdx.x;
    const int lane = t & 63, w = t >> 6;
    const int wm = w >> 1, wn = w & 1;
    const int r = lane & 15, g = lane >> 4;

    f32x4 acc[4][4];
#pragma unroll
    for (int mi = 0; mi < 4; mi++)
#pragma unroll
        for (int ni = 0; ni < 4; ni++)
#pragma unroll
            for (int k = 0; k < 4; k++) acc[mi][ni][k] = 0.f;

    const float* Abase = A + (long)mb * BM * K_;
    const unsigned short* Bbase = Bw + (long)nb * BN * K_;

    for (int kt = 0; kt < K_; kt += BK) {
        __syncthreads();
        // stage B: async DMA global->LDS, 16B/lane; lds offset = u*16B (contiguous per wave)
#pragma unroll
        for (int j = 0; j < 2; j++) {
            int u = t + 256 * j;
            int row = u >> 2, c8 = (u & 3) << 3;
            __builtin_amdgcn_global_load_lds(
                (const __attribute__((address_space(1))) unsigned*)(Bbase + (long)row * K_ + kt + c8),
                (__attribute__((address_space(3))) unsigned*)&Bsm[u * 8],
                16, 0, 0);
        }
        // stage A: fp32 load -> packed cvt -> LDS (padded)
#pragma unroll
        for (int i = 0; i < 4; i++) {
            int f = t + 256 * i;
            int row = f >> 3, c4 = (f & 7) << 2;
            float4 v = *(const float4*)(Abase + (long)row * K_ + kt + c4);
            uint2 pk;
            pk.x = pk_bf16(v.x, v.y);
            pk.y = pk_bf16(v.z, v.w);
            *(uint2*)&Asm[row * LDK + c4] = pk;
        }
        __syncthreads();
        bf16x8 af[4], bfr[4];
#pragma unroll
        for (int mi = 0; mi < 4; mi++)
            af[mi] = *(const bf16x8*)&Asm[(wm * 64 + mi * 16 + r) * LDK + g * 8];
#pragma unroll
        for (int ni = 0; ni < 4; ni++)
            bfr[ni] = *(const bf16x8*)&Bsm[(wn * 64 + ni * 16 + r) * BK + g * 8];
#pragma unroll
        for (int mi = 0; mi < 4; mi++)
#pragma unroll
            for (int ni = 0; ni < 4; ni++)
                acc[mi][ni] = __builtin_amdgcn_mfma_f32_16x16x32_bf16(af[mi], bfr[ni],
                                                                     acc[mi][ni], 0, 0, 0);
    }

    // ---- epilogue: partial energies for this 128-col slab ----
    const int b = mb >> 4;  // S/BM = 16 m-blocks per batch; tiles never straddle b
    float wv[4], dv[4];
#pragma unroll
    for (int ni = 0; ni < 4; ni++) {
        int h = nb * BN + wn * 64 + ni * 16 + r;  // C/D col = lane&15
        wv[ni] = Weng[h];
        dv[ni] = decv[b * H_ + h];
    }
    float rs[4][4];
#pragma unroll
    for (int mi = 0; mi < 4; mi++)
#pragma unroll
        for (int rr = 0; rr < 4; rr++) rs[mi][rr] = 0.f;
#pragma unroll
    for (int mi = 0; mi < 4; mi++)
#pragma unroll
        for (int ni = 0; ni < 4; ni++)
#pragma unroll
            for (int rr = 0; rr < 4; rr++)
                rs[mi][rr] += wv[ni] * tanh_fast(dv[ni] + acc[mi][ni][rr]);
#pragma unroll
    for (int m2 = 1; m2 < 16; m2 <<= 1)
#pragma unroll
        for (int mi = 0; mi < 4; mi++)
#pragma unroll
            for (int rr = 0; rr < 4; rr++)
                rs[mi][rr] += __shfl_xor(rs[mi][rr], m2, 64);
    if (r == 0) {
#pragma unroll
        for (int mi = 0; mi < 4; mi++)
#pragma unroll
            for (int rr = 0; rr < 4; rr++)
                esum[wn][wm * 64 + mi * 16 + g * 4 + rr] = rs[mi][rr];  // row=(lane>>4)*4+reg
    }
    __syncthreads();
    if (t < BM) pe[(long)nb * M_ + (long)mb * BM + t] = esum[0][t] + esum[1][t];
}

// ---------------------------------------------------------------- masked softmax over s
__global__ __launch_bounds__(256) void softmax_k(const float* __restrict__ pe,
                                                 const int* __restrict__ slen,
                                                 float* __restrict__ alph) {
    const int b = blockIdx.x, t = threadIdx.x;
    const int len = slen[b];
    __shared__ float sh[4];
    const float NEG = -__builtin_inff();
    float e[8];
    float mx = NEG;
#pragma unroll
    for (int i = 0; i < 8; i++) {
        int s = t + i * 256;
        float v = 0.f;
#pragma unroll
        for (int p = 0; p < 8; p++) v += pe[(long)p * M_ + b * S_ + s];
        v = (s < len) ? v : NEG;
        e[i] = v;
        mx = fmaxf(mx, v);
    }
    for (int m2 = 1; m2 < 64; m2 <<= 1) mx = fmaxf(mx, __shfl_xor(mx, m2, 64));
    if ((t & 63) == 0) sh[t >> 6] = mx;
    __syncthreads();
    mx = fmaxf(fmaxf(sh[0], sh[1]), fmaxf(sh[2], sh[3]));
    float sum = 0.f;
#pragma unroll
    for (int i = 0; i < 8; i++) {
        float x = (e[i] == NEG) ? 0.f : __expf(e[i] - mx);
        e[i] = x;
        sum += x;
    }
    for (int m2 = 1; m2 < 64; m2 <<= 1) sum += __shfl_xor(sum, m2, 64);
    __syncthreads();
    if ((t & 63) == 0) sh[t >> 6] = sum;
    __syncthreads();
    sum = sh[0] + sh[1] + sh[2] + sh[3];
    float inv = 1.0f / sum;
#pragma unroll
    for (int i = 0; i < 8; i++) alph[b * S_ + t + i * 256] = e[i] * inv;
}

// ---------------------------------------------------------------- context = alphas @ enc_state
__global__ __launch_bounds__(256) void context_k(const float* __restrict__ enc,
                                                 const float* __restrict__ alph,
                                                 const int* __restrict__ slen,
                                                 float* __restrict__ out) {
    const int b = blockIdx.y;
    const int x = blockIdx.x;
    const int ec = x & 1, sc = x >> 1;  // 2 e-halves x 8 s-chunks
    const int len = slen[b];
    const int s0 = sc * 256;
    if (s0 >= len) return;  // alphas there are exactly 0
    const int send = min(s0 + 256, len);
    __shared__ float al[256];
    const int t = threadIdx.x;
    al[t] = alph[b * S_ + s0 + t];
    __syncthreads();
    const int e0 = ec * 1024 + t * 4;
    float ax = 0.f, ay = 0.f, az = 0.f, aw = 0.f;
    const float* base = enc + ((long)b * S_ + s0) * K_ + e0;
#pragma unroll 4
    for (int s = s0; s < send; ++s) {
        float a = al[s - s0];
        float4 v = *(const float4*)base;
        ax += a * v.x; ay += a * v.y; az += a * v.z; aw += a * v.w;
        base += K_;
    }
    float* o = out + (long)b * K_ + e0;
    atomicAdd(o + 0, ax);
    atomicAdd(o + 1, ay);
    atomicAdd(o + 2, az);
    atomicAdd(o + 3, aw);
}

extern "C" void kernel_launch(void* const* d_in, const int* in_sizes, int n_in,
                              void* d_out, int out_size, void* d_ws, size_t ws_size,
                              hipStream_t stream) {
    const float* dec_state = (const float*)d_in[0];  // [32,1,1024]
    const float* enc_state = (const float*)d_in[1];  // [32,2048,2048]
    const int*   src_len   = (const int*)d_in[2];    // [32]
    const float* W_enc     = (const float*)d_in[3];  // [1024,2048]
    const float* W_dec     = (const float*)d_in[4];  // [1024,1024]
    const float* W_energy  = (const float*)d_in[5];  // [1,1024]
    float* out = (float*)d_out;  // [0,65536): context [32,2048]; [65536,131072): alphas [32,2048]

    char* ws = (char*)d_ws;
    float* decv = (float*)ws;                                           // 128 KB
    float* pe   = (float*)(ws + 131072);                                // 2 MB
    unsigned short* Wenc_bf = (unsigned short*)(ws + 131072 + 2097152); // 4 MB
    float* alph = out + 65536;

    hipMemsetAsync(out, 0, 65536 * sizeof(float), stream);

    cast_k<<<2048, 256, 0, stream>>>(W_enc, Wenc_bf, 524288);
    dec_k<<<dim3(H_ / 4, B_), 256, 0, stream>>>(dec_state, W_dec, decv);
    gemm_energy<<<4096, 256, 0, stream>>>(enc_state, Wenc_bf, decv, W_energy, pe);
    softmax_k<<<B_, 256, 0, stream>>>(pe, src_len, alph);
    context_k<<<dim3(16, B_), 256, 0, stream>>>(enc_state, alph, src_len, out);
}

// Round 3
// 1130.449 us; speedup vs baseline: 1.0755x; 1.0211x over previous
//
#include <hip/hip_runtime.h>
#include <hip/hip_bf16.h>
#include <stdint.h>

// Problem constants
#define B_  32
#define S_  2048
#define H_  1024
#define K_  2048   // 2H, GEMM reduction dim
#define M_  65536  // B*S

// GEMM tile config
#define BM  128
#define BN  128
#define BK  32
#define LDK 40     // padded LDS row stride for A in fallback path (bf16 elems)

typedef __bf16 bf16x8 __attribute__((ext_vector_type(8)));
typedef float  f32x4  __attribute__((ext_vector_type(4)));

__device__ __forceinline__ unsigned short f2bf(float x) {
    unsigned u = __builtin_bit_cast(unsigned, x);
    u += 0x7fffu + ((u >> 16) & 1u);
    return (unsigned short)(u >> 16);
}

__device__ __forceinline__ unsigned pk_bf16(float x, float y) {
#if __has_builtin(__builtin_amdgcn_cvt_pk_bf16_f32)
    auto r = __builtin_amdgcn_cvt_pk_bf16_f32(x, y);
    static_assert(sizeof(r) == 4, "cvt_pk_bf16 size");
    return __builtin_bit_cast(unsigned, r);
#else
    return ((unsigned)f2bf(x)) | ((unsigned)f2bf(y) << 16);
#endif
}

__device__ __forceinline__ float bf2f(unsigned u16) {
    return __builtin_bit_cast(float, u16 << 16);
}

__device__ __forceinline__ float tanh_fast(float x) {
    float e = __expf(2.0f * x);
    return 1.0f - 2.0f / (e + 1.0f);
}

// ---------------------------------------------------------------- fp32 -> bf16, 8 elems/thread
__global__ __launch_bounds__(256) void cast8_k(const float* __restrict__ in,
                                               unsigned short* __restrict__ o, long n8) {
    long i = (long)blockIdx.x * 256 + threadIdx.x;
    if (i < n8) {
        const float4* p = (const float4*)(in + i * 8);
        float4 a = p[0], b = p[1];
        uint4 pk;
        pk.x = pk_bf16(a.x, a.y);
        pk.y = pk_bf16(a.z, a.w);
        pk.z = pk_bf16(b.x, b.y);
        pk.w = pk_bf16(b.z, b.w);
        *(uint4*)(o + i * 8) = pk;
    }
}

// ---------------------------------------------------------------- dec = dec_state @ W_dec^T
__global__ __launch_bounds__(256) void dec_k(const float* __restrict__ ds,
                                             const float* __restrict__ Wd,
                                             float* __restrict__ decv) {
    const int b = blockIdx.y;
    const int w = threadIdx.x >> 6, lane = threadIdx.x & 63;
    const int h = blockIdx.x * 4 + w;
    const float* wr = Wd + (long)h * H_;
    const float* dr = ds + (long)b * H_;
    float acc = 0.f;
#pragma unroll
    for (int i = 0; i < 4; i++) {
        int idx = lane * 4 + i * 256;
        float4 a = *(const float4*)(wr + idx);
        float4 d = *(const float4*)(dr + idx);
        acc += a.x * d.x + a.y * d.y + a.z * d.z + a.w * d.w;
    }
    for (int m2 = 1; m2 < 64; m2 <<= 1) acc += __shfl_xor(acc, m2, 64);
    if (lane == 0) decv[(long)b * H_ + h] = acc;
}

// ---------------------------------------------------------------- shared epilogue
__device__ __forceinline__ void energy_epilogue(f32x4 acc[4][4], int mb, int nb,
                                                const float* decv, const float* Weng,
                                                float* pe, float esum[2][BM],
                                                int t, int wm, int wn, int r, int g) {
    const int b = mb >> 4;  // S/BM = 16 m-blocks per batch; tiles never straddle b
    float wv[4], dv[4];
#pragma unroll
    for (int ni = 0; ni < 4; ni++) {
        int h = nb * BN + wn * 64 + ni * 16 + r;  // C/D col = lane&15
        wv[ni] = Weng[h];
        dv[ni] = decv[b * H_ + h];
    }
    float rs[4][4];
#pragma unroll
    for (int mi = 0; mi < 4; mi++)
#pragma unroll
        for (int rr = 0; rr < 4; rr++) rs[mi][rr] = 0.f;
#pragma unroll
    for (int mi = 0; mi < 4; mi++)
#pragma unroll
        for (int ni = 0; ni < 4; ni++)
#pragma unroll
            for (int rr = 0; rr < 4; rr++)
                rs[mi][rr] += wv[ni] * tanh_fast(dv[ni] + acc[mi][ni][rr]);
#pragma unroll
    for (int m2 = 1; m2 < 16; m2 <<= 1)
#pragma unroll
        for (int mi = 0; mi < 4; mi++)
#pragma unroll
            for (int rr = 0; rr < 4; rr++)
                rs[mi][rr] += __shfl_xor(rs[mi][rr], m2, 64);
    if (r == 0) {
#pragma unroll
        for (int mi = 0; mi < 4; mi++)
#pragma unroll
            for (int rr = 0; rr < 4; rr++)
                esum[wn][wm * 64 + mi * 16 + g * 4 + rr] = rs[mi][rr];  // row=(lane>>4)*4+reg
    }
    __syncthreads();
    if (t < BM) pe[(long)nb * M_ + (long)mb * BM + t] = esum[0][t] + esum[1][t];
}

// ---------------------------------------------------------------- FAST gemm: A,B both bf16, DMA staging
__global__ __launch_bounds__(256) void gemm_fast(const unsigned short* __restrict__ Abf,
                                                 const unsigned short* __restrict__ Bw,
                                                 const float* __restrict__ decv,
                                                 const float* __restrict__ Weng,
                                                 float* __restrict__ pe) {
    __shared__ __align__(1024) unsigned short Asm[BM * BK];  // unpadded: DMA-contiguous
    __shared__ __align__(1024) unsigned short Bsm[BN * BK];
    __shared__ float esum[2][BM];

    // XCD-group swizzle: 8 nb-blocks of an mb land on one XCD, adjacent in dispatch.
    const int L = blockIdx.x;
    const int xcd = L & 7;
    const int slot = L >> 3;
    const int nb = slot & 7;
    const int mb = (slot >> 3) * 8 + xcd;

    const int t = threadIdx.x;
    const int lane = t & 63, w = t >> 6;
    const int wm = w >> 1, wn = w & 1;
    const int r = lane & 15, g = lane >> 4;

    f32x4 acc[4][4];
#pragma unroll
    for (int mi = 0; mi < 4; mi++)
#pragma unroll
        for (int ni = 0; ni < 4; ni++)
#pragma unroll
            for (int k = 0; k < 4; k++) acc[mi][ni][k] = 0.f;

    const unsigned short* Abase = Abf + (long)mb * BM * K_;
    const unsigned short* Bbase = Bw + (long)nb * BN * K_;

    for (int kt = 0; kt < K_; kt += BK) {
        __syncthreads();
#pragma unroll
        for (int j = 0; j < 2; j++) {
            int u = t + 256 * j;
            int row = u >> 2, c8 = (u & 3) << 3;
            __builtin_amdgcn_global_load_lds(
                (const __attribute__((address_space(1))) unsigned*)(Abase + (long)row * K_ + kt + c8),
                (__attribute__((address_space(3))) unsigned*)&Asm[u * 8], 16, 0, 0);
        }
#pragma unroll
        for (int j = 0; j < 2; j++) {
            int u = t + 256 * j;
            int row = u >> 2, c8 = (u & 3) << 3;
            __builtin_amdgcn_global_load_lds(
                (const __attribute__((address_space(1))) unsigned*)(Bbase + (long)row * K_ + kt + c8),
                (__attribute__((address_space(3))) unsigned*)&Bsm[u * 8], 16, 0, 0);
        }
        __syncthreads();
        bf16x8 af[4], bfr[4];
#pragma unroll
        for (int mi = 0; mi < 4; mi++)
            af[mi] = *(const bf16x8*)&Asm[(wm * 64 + mi * 16 + r) * BK + g * 8];
#pragma unroll
        for (int ni = 0; ni < 4; ni++)
            bfr[ni] = *(const bf16x8*)&Bsm[(wn * 64 + ni * 16 + r) * BK + g * 8];
#pragma unroll
        for (int mi = 0; mi < 4; mi++)
#pragma unroll
            for (int ni = 0; ni < 4; ni++)
                acc[mi][ni] = __builtin_amdgcn_mfma_f32_16x16x32_bf16(af[mi], bfr[ni],
                                                                     acc[mi][ni], 0, 0, 0);
    }
    energy_epilogue(acc, mb, nb, decv, Weng, pe, esum, t, wm, wn, r, g);
}

// ---------------------------------------------------------------- FALLBACK gemm (fp32 A, in-kernel cvt)
__global__ __launch_bounds__(256) void gemm_energy(const float* __restrict__ A,
                                                   const unsigned short* __restrict__ Bw,
                                                   const float* __restrict__ decv,
                                                   const float* __restrict__ Weng,
                                                   float* __restrict__ pe) {
    __shared__ __align__(16) unsigned short Asm[BM * LDK];
    __shared__ __align__(1024) unsigned short Bsm[BN * BK];
    __shared__ float esum[2][BM];

    const int L = blockIdx.x;
    const int xcd = L & 7;
    const int slot = L >> 3;
    const int nb = slot & 7;
    const int mb = (slot >> 3) * 8 + xcd;

    const int t = threadIdx.x;
    const int lane = t & 63, w = t >> 6;
    const int wm = w >> 1, wn = w & 1;
    const int r = lane & 15, g = lane >> 4;

    f32x4 acc[4][4];
#pragma unroll
    for (int mi = 0; mi < 4; mi++)
#pragma unroll
        for (int ni = 0; ni < 4; ni++)
#pragma unroll
            for (int k = 0; k < 4; k++) acc[mi][ni][k] = 0.f;

    const float* Abase = A + (long)mb * BM * K_;
    const unsigned short* Bbase = Bw + (long)nb * BN * K_;

    for (int kt = 0; kt < K_; kt += BK) {
        __syncthreads();
#pragma unroll
        for (int j = 0; j < 2; j++) {
            int u = t + 256 * j;
            int row = u >> 2, c8 = (u & 3) << 3;
            __builtin_amdgcn_global_load_lds(
                (const __attribute__((address_space(1))) unsigned*)(Bbase + (long)row * K_ + kt + c8),
                (__attribute__((address_space(3))) unsigned*)&Bsm[u * 8], 16, 0, 0);
        }
#pragma unroll
        for (int i = 0; i < 4; i++) {
            int f = t + 256 * i;
            int row = f >> 3, c4 = (f & 7) << 2;
            float4 v = *(const float4*)(Abase + (long)row * K_ + kt + c4);
            uint2 pk;
            pk.x = pk_bf16(v.x, v.y);
            pk.y = pk_bf16(v.z, v.w);
            *(uint2*)&Asm[row * LDK + c4] = pk;
        }
        __syncthreads();
        bf16x8 af[4], bfr[4];
#pragma unroll
        for (int mi = 0; mi < 4; mi++)
            af[mi] = *(const bf16x8*)&Asm[(wm * 64 + mi * 16 + r) * LDK + g * 8];
#pragma unroll
        for (int ni = 0; ni < 4; ni++)
            bfr[ni] = *(const bf16x8*)&Bsm[(wn * 64 + ni * 16 + r) * BK + g * 8];
#pragma unroll
        for (int mi = 0; mi < 4; mi++)
#pragma unroll
            for (int ni = 0; ni < 4; ni++)
                acc[mi][ni] = __builtin_amdgcn_mfma_f32_16x16x32_bf16(af[mi], bfr[ni],
                                                                     acc[mi][ni], 0, 0, 0);
    }
    energy_epilogue(acc, mb, nb, decv, Weng, pe, esum, t, wm, wn, r, g);
}

// ---------------------------------------------------------------- masked softmax over s
__global__ __launch_bounds__(256) void softmax_k(const float* __restrict__ pe,
                                                 const int* __restrict__ slen,
                                                 float* __restrict__ alph) {
    const int b = blockIdx.x, t = threadIdx.x;
    const int len = slen[b];
    __shared__ float sh[4];
    const float NEG = -__builtin_inff();
    float e[8];
    float mx = NEG;
#pragma unroll
    for (int i = 0; i < 8; i++) {
        int s = t + i * 256;
        float v = 0.f;
#pragma unroll
        for (int p = 0; p < 8; p++) v += pe[(long)p * M_ + b * S_ + s];
        v = (s < len) ? v : NEG;
        e[i] = v;
        mx = fmaxf(mx, v);
    }
    for (int m2 = 1; m2 < 64; m2 <<= 1) mx = fmaxf(mx, __shfl_xor(mx, m2, 64));
    if ((t & 63) == 0) sh[t >> 6] = mx;
    __syncthreads();
    mx = fmaxf(fmaxf(sh[0], sh[1]), fmaxf(sh[2], sh[3]));
    float sum = 0.f;
#pragma unroll
    for (int i = 0; i < 8; i++) {
        float x = (e[i] == NEG) ? 0.f : __expf(e[i] - mx);
        e[i] = x;
        sum += x;
    }
    for (int m2 = 1; m2 < 64; m2 <<= 1) sum += __shfl_xor(sum, m2, 64);
    __syncthreads();
    if ((t & 63) == 0) sh[t >> 6] = sum;
    __syncthreads();
    sum = sh[0] + sh[1] + sh[2] + sh[3];
    float inv = 1.0f / sum;
#pragma unroll
    for (int i = 0; i < 8; i++) alph[b * S_ + t + i * 256] = e[i] * inv;
}

// ---------------------------------------------------------------- context (bf16 enc copy), fine-grained
// 1024 slots: b = slot&31, sc = slot>>5 (64-row s-chunk). 256 thr x 8 cols = full 2048.
__global__ __launch_bounds__(256) void context_bf(const unsigned short* __restrict__ encbf,
                                                  const float* __restrict__ alph,
                                                  const int* __restrict__ slen,
                                                  float* __restrict__ out) {
    const int slot = blockIdx.x;
    const int b = slot & 31, sc = slot >> 5;
    const int len = slen[b];
    const int s0 = sc * 64;
    if (s0 >= len) return;
    const int send = min(s0 + 64, len);
    __shared__ float al[64];
    const int t = threadIdx.x;
    if (t < 64) al[t] = alph[b * S_ + s0 + t];
    __syncthreads();
    const unsigned short* base = encbf + ((long)b * S_ + s0) * K_ + t * 8;
    float ac[8];
#pragma unroll
    for (int j = 0; j < 8; j++) ac[j] = 0.f;
#pragma unroll 4
    for (int s = s0; s < send; ++s) {
        float a = al[s - s0];
        uint4 v = *(const uint4*)base;
        ac[0] += a * bf2f(v.x & 0xffffu);
        ac[1] += a * bf2f(v.x >> 16);
        ac[2] += a * bf2f(v.y & 0xffffu);
        ac[3] += a * bf2f(v.y >> 16);
        ac[4] += a * bf2f(v.z & 0xffffu);
        ac[5] += a * bf2f(v.z >> 16);
        ac[6] += a * bf2f(v.w & 0xffffu);
        ac[7] += a * bf2f(v.w >> 16);
        base += K_;
    }
    float* o = out + (long)b * K_ + t * 8;
#pragma unroll
    for (int j = 0; j < 8; j++) atomicAdd(o + j, ac[j]);
}

// ---------------------------------------------------------------- context (fp32), fine-grained fallback
// 2048 slots: b = slot&31, ec = (slot>>5)&1, sc = slot>>6. 256 thr x float4.
__global__ __launch_bounds__(256) void context_f32(const float* __restrict__ enc,
                                                   const float* __restrict__ alph,
                                                   const int* __restrict__ slen,
                                                   float* __restrict__ out) {
    const int slot = blockIdx.x;
    const int b = slot & 31, ec = (slot >> 5) & 1, sc = slot >> 6;
    const int len = slen[b];
    const int s0 = sc * 64;
    if (s0 >= len) return;
    const int send = min(s0 + 64, len);
    __shared__ float al[64];
    const int t = threadIdx.x;
    if (t < 64) al[t] = alph[b * S_ + s0 + t];
    __syncthreads();
    const int e0 = ec * 1024 + t * 4;
    const float* base = enc + ((long)b * S_ + s0) * K_ + e0;
    float ax = 0.f, ay = 0.f, az = 0.f, aw = 0.f;
#pragma unroll 4
    for (int s = s0; s < send; ++s) {
        float a = al[s - s0];
        float4 v = *(const float4*)base;
        ax += a * v.x; ay += a * v.y; az += a * v.z; aw += a * v.w;
        base += K_;
    }
    float* o = out + (long)b * K_ + e0;
    atomicAdd(o + 0, ax);
    atomicAdd(o + 1, ay);
    atomicAdd(o + 2, az);
    atomicAdd(o + 3, aw);
}

extern "C" void kernel_launch(void* const* d_in, const int* in_sizes, int n_in,
                              void* d_out, int out_size, void* d_ws, size_t ws_size,
                              hipStream_t stream) {
    const float* dec_state = (const float*)d_in[0];  // [32,1,1024]
    const float* enc_state = (const float*)d_in[1];  // [32,2048,2048]
    const int*   src_len   = (const int*)d_in[2];    // [32]
    const float* W_enc     = (const float*)d_in[3];  // [1024,2048]
    const float* W_dec     = (const float*)d_in[4];  // [1024,1024]
    const float* W_energy  = (const float*)d_in[5];  // [1,1024]
    float* out = (float*)d_out;  // [0,65536): context [32,2048]; [65536,131072): alphas [32,2048]

    char* ws = (char*)d_ws;
    float* decv = (float*)ws;                                           // 128 KB @ 0
    float* pe   = (float*)(ws + (1 << 17));                             // 2 MB @ 128K
    unsigned short* Wenc_bf = (unsigned short*)(ws + 3 * (1 << 20));    // 4 MB @ 3M
    unsigned short* Abf = (unsigned short*)(ws + 8 * (1 << 20));        // 256 MB @ 8M
    float* alph = out + 65536;

    const size_t need_fast = 8ull * (1 << 20) + (size_t)M_ * K_ * 2;  // 8M + 256M

    hipMemsetAsync(out, 0, 65536 * sizeof(float), stream);

    cast8_k<<<1024, 256, 0, stream>>>(W_enc, Wenc_bf, (long)H_ * K_ / 8);
    dec_k<<<dim3(H_ / 4, B_), 256, 0, stream>>>(dec_state, W_dec, decv);

    if (ws_size >= need_fast) {
        cast8_k<<<65536, 256, 0, stream>>>(enc_state, Abf, (long)M_ * K_ / 8);
        gemm_fast<<<4096, 256, 0, stream>>>(Abf, Wenc_bf, decv, W_energy, pe);
        softmax_k<<<B_, 256, 0, stream>>>(pe, src_len, alph);
        context_bf<<<1024, 256, 0, stream>>>(Abf, alph, src_len, out);
    } else {
        gemm_energy<<<4096, 256, 0, stream>>>(enc_state, Wenc_bf, decv, W_energy, pe);
        softmax_k<<<B_, 256, 0, stream>>>(pe, src_len, alph);
        context_f32<<<2048, 256, 0, stream>>>(enc_state, alph, src_len, out);
    }
}